// Round 4
// baseline (1877.112 us; speedup 1.0000x reference)
//
#include <hip/hip_runtime.h>
#include <hip/hip_bf16.h>

#define BATCH   16
#define SEQ     4096
#define HID     4096
#define NHEADS  32
#define NKVH    8
#define HDIM    128
#define NREPS   4
#define QKV_DIM 6144    // (32 + 2*8) * 128
#define NSCH    64      // S-chunks for flash decode
#define SCH     64      // positions per chunk
#define NBLK    1024    // persistent grid (4 blocks/CU, guaranteed resident)
#define KC4     64      // float4 per GEMV K-chunk

// ---------------------------------------------------------------------------
// Device-scope sense-reversal grid barrier. bar[0]=counter, bar[16]=generation
// (separate cachelines). Requires all NBLK blocks co-resident.
// ---------------------------------------------------------------------------
__device__ __forceinline__ void grid_barrier(unsigned* bar) {
  __threadfence();                 // release my stores to device scope
  __syncthreads();                 // order whole block before arrival
  if (threadIdx.x == 0) {
    unsigned gen = __hip_atomic_load(&bar[16], __ATOMIC_RELAXED,
                                     __HIP_MEMORY_SCOPE_AGENT);
    unsigned prev = __hip_atomic_fetch_add(&bar[0], 1u, __ATOMIC_ACQ_REL,
                                           __HIP_MEMORY_SCOPE_AGENT);
    if (prev == (unsigned)(NBLK - 1)) {
      __hip_atomic_store(&bar[0], 0u, __ATOMIC_RELAXED,
                         __HIP_MEMORY_SCOPE_AGENT);
      __hip_atomic_fetch_add(&bar[16], 1u, __ATOMIC_RELEASE,
                             __HIP_MEMORY_SCOPE_AGENT);
    } else {
      while (__hip_atomic_load(&bar[16], __ATOMIC_ACQUIRE,
                               __HIP_MEMORY_SCOPE_AGENT) == gen)
        __builtin_amdgcn_s_sleep(2);
    }
  }
  __syncthreads();
  __threadfence();                 // acquire: invalidate stale cached data
}

// ---------------------------------------------------------------------------
// One persistent kernel, 6 stages, 5 grid barriers.
// ---------------------------------------------------------------------------
__global__ __launch_bounds__(256, 4) void fused(
    const float4* __restrict__ x4,        // [16][1024]
    const int*    __restrict__ last_pos,  // [16]
    const float2* __restrict__ rope2,     // [SEQ][64]
    const float4* __restrict__ wqkv4,     // [6144][1024]
    const float4* __restrict__ oproj4,    // [4096][1024]
    const float*  __restrict__ cache_k,   // [16][SEQ][8][128]
    const float*  __restrict__ cache_v,
    float* __restrict__ out,              // [16][4096]
    float* __restrict__ ws)
{
  __shared__ float shbuf[4096];          // 16 KB, reused per stage

  unsigned* bar   = (unsigned*)ws;       // 64 floats reserved
  float* qkv_part = ws + 64;                                  // 2*16*6144
  float* proc     = qkv_part + 2 * BATCH * QKV_DIM;           // 16*6144
  float* part_out = proc + BATCH * QKV_DIM;                   // 16*64*8*4*128
  float* part_ml  = part_out + (long)BATCH * NSCH * NKVH * NREPS * HDIM;
  float* attn_out = part_ml + BATCH * NSCH * NKVH * NREPS * 2;
  float* out_part = attn_out + BATCH * HID;                   // 2*16*4096

  const int tid  = threadIdx.x;
  const int wid  = tid >> 6;
  const int lane = tid & 63;

  // ======== S1: qkv_part[ks][b][m] = x[b] . wqkv[m], K-split 2 ========
  {
    float4* xs = (float4*)shbuf;         // [16][KC4]
    for (int t = blockIdx.x; t < 1536; t += NBLK) {
      const int ks = t / 768, rb = t % 768;
      const int row0 = rb * 8 + wid * 2;
      const int k0 = ks * 512;
      float acc[16][2];
#pragma unroll
      for (int b = 0; b < 16; ++b) { acc[b][0] = 0.f; acc[b][1] = 0.f; }

      for (int c = 0; c < 512; c += KC4) {
        __syncthreads();
#pragma unroll
        for (int i = tid; i < 16 * KC4; i += 256)
          xs[i] = x4[((i >> 6) << 10) + k0 + c + (i & 63)];
        __syncthreads();
        const long wb = (long)row0 * 1024 + k0 + c + lane;
        float4 w0 = wqkv4[wb];
        float4 w1 = wqkv4[wb + 1024];
#pragma unroll
        for (int b = 0; b < 16; ++b) {
          float4 xv = xs[(b << 6) + lane];
          acc[b][0] = fmaf(w0.x,xv.x,fmaf(w0.y,xv.y,fmaf(w0.z,xv.z,fmaf(w0.w,xv.w,acc[b][0]))));
          acc[b][1] = fmaf(w1.x,xv.x,fmaf(w1.y,xv.y,fmaf(w1.z,xv.z,fmaf(w1.w,xv.w,acc[b][1]))));
        }
      }
#pragma unroll
      for (int b = 0; b < 16; ++b) {
#pragma unroll
        for (int r = 0; r < 2; ++r) {
          float v = acc[b][r];
#pragma unroll
          for (int o = 32; o; o >>= 1) v += __shfl_xor(v, o, 64);
          if (lane == 0)
            qkv_part[((long)(ks * 16 + b)) * QKV_DIM + row0 + r] = v;
        }
      }
    }
  }
  grid_barrier(bar);

  // ======== S2: reduce halves + RoPE + RMSNorm (one wave per (b,head)) ====
  {
    const int widx = blockIdx.x * 4 + wid;
    if (widx < 768) {
      const int b = widx / 48, hh = widx % 48;   // 0..31 q, 32..39 k, 40..47 v
      const int off = b * QKV_DIM + hh * HDIM;
      float2 e0 = ((const float2*)(qkv_part + off))[lane];
      float2 e1 = ((const float2*)(qkv_part + BATCH * QKV_DIM + off))[lane];
      float ex = e0.x + e1.x, ey = e0.y + e1.y;
      float r0 = ex, r1 = ey;
      if (hh < 40) {
        const int pos = last_pos[b];
        float2 cs = rope2[pos * 64 + lane];
        r0 = ex * cs.x - ey * cs.y;
        r1 = ey * cs.x + ex * cs.y;
        float ss = r0 * r0 + r1 * r1;
#pragma unroll
        for (int o = 32; o; o >>= 1) ss += __shfl_xor(ss, o, 64);
        float scl = rsqrtf(ss * (1.0f / 128.0f) + 1e-5f);
        r0 *= scl; r1 *= scl;
      }
      ((float2*)(proc + off))[lane] = make_float2(r0, r1);
    }
  }
  grid_barrier(bar);

  // ======== S3: attention partials. task = (b, ch); half-wave per group ====
  {
    float (*sc)[NREPS][SCH] = (float (*)[NREPS][SCH])shbuf;   // [8][4][64] 8KB
    const int task = blockIdx.x;
    const int ch = task & (NSCH - 1);
    const int b  = task >> 6;
    const int pos = last_pos[b];
    const int s0 = ch * SCH;

    const int g   = tid >> 5;
    const int sub = tid & 31;
    const int r   = sub >> 3;
    const int sl  = sub & 7;

    const float4* kg = (const float4*)(cache_k + ((long)b * SEQ * NKVH) * HDIM) + g * 32;
    const float4* vg = (const float4*)(cache_v + ((long)b * SEQ * NKVH) * HDIM) + g * 32;
    const float4* knewg = (const float4*)(proc + b * QKV_DIM + (NHEADS + g) * HDIM);
    const float4* vnewg = (const float4*)(proc + b * QKV_DIM + (NHEADS + NKVH + g) * HDIM);

    const float isq = 0.08838834764831845f;
    float4 ql[4];
#pragma unroll
    for (int t = 0; t < 4; ++t) {
      float4 q = *(const float4*)(proc + b * QKV_DIM + (g * NREPS + r) * HDIM + sl * 16 + t * 4);
      ql[t] = make_float4(q.x * isq, q.y * isq, q.z * isq, q.w * isq);
    }

    float m = -3e38f;
#pragma unroll 8
    for (int i = 0; i < SCH; ++i) {
      const int s = s0 + i;
      const float4* row = (s == pos) ? knewg : (kg + (long)s * 256);
      float d = 0.f;
#pragma unroll
      for (int t = 0; t < 4; ++t) {
        float4 kv = row[sl * 4 + t];
        d += kv.x*ql[t].x + kv.y*ql[t].y + kv.z*ql[t].z + kv.w*ql[t].w;
      }
      d += __shfl_xor(d, 1); d += __shfl_xor(d, 2); d += __shfl_xor(d, 4);
      if (sl == 0) sc[g][r][i] = d;
      m = fmaxf(m, d);
    }

    float lsum = 0.f;
#pragma unroll
    for (int i = sl; i < SCH; i += 8) {
      float e = __expf(sc[g][r][i] - m);
      sc[g][r][i] = e;
      lsum += e;
    }
    lsum += __shfl_xor(lsum, 1); lsum += __shfl_xor(lsum, 2); lsum += __shfl_xor(lsum, 4);

    const long mlbase = ((((long)b * NSCH + ch) * NKVH + g) * NREPS + r) * 2;
    if (sl == 0) { part_ml[mlbase] = m; part_ml[mlbase + 1] = lsum; }

    const int dq = sub;
    float4 a0 = {0,0,0,0}, a1 = {0,0,0,0}, a2 = {0,0,0,0}, a3 = {0,0,0,0};
#pragma unroll 8
    for (int i = 0; i < SCH; ++i) {
      const int s = s0 + i;
      const float4* row = (s == pos) ? vnewg : (vg + (long)s * 256);
      float4 vv = row[dq];
      float p0 = sc[g][0][i], p1 = sc[g][1][i], p2 = sc[g][2][i], p3 = sc[g][3][i];
      a0.x += p0*vv.x; a0.y += p0*vv.y; a0.z += p0*vv.z; a0.w += p0*vv.w;
      a1.x += p1*vv.x; a1.y += p1*vv.y; a1.z += p1*vv.z; a1.w += p1*vv.w;
      a2.x += p2*vv.x; a2.y += p2*vv.y; a2.z += p2*vv.z; a2.w += p2*vv.w;
      a3.x += p3*vv.x; a3.y += p3*vv.y; a3.z += p3*vv.z; a3.w += p3*vv.w;
    }
    float* pb = part_out + (((long)b * NSCH + ch) * NKVH + g) * NREPS * HDIM + dq * 4;
    *(float4*)(pb)            = a0;
    *(float4*)(pb + HDIM)     = a1;
    *(float4*)(pb + 2 * HDIM) = a2;
    *(float4*)(pb + 3 * HDIM) = a3;
  }
  grid_barrier(bar);

  // ======== S4: combine chunk partials (blocks 0..511, threads 0..127) ====
  if (blockIdx.x < 512 && tid < 128) {
    const int r = blockIdx.x & 3;
    const int g = (blockIdx.x >> 2) & 7;
    const int b = blockIdx.x >> 5;
    const int d = tid;

    float M = -3e38f;
#pragma unroll 8
    for (int c = 0; c < NSCH; ++c) {
      const long idx = ((((long)b * NSCH + c) * NKVH + g) * NREPS + r) * 2;
      M = fmaxf(M, part_ml[idx]);
    }
    float L = 0.f, o = 0.f;
#pragma unroll 8
    for (int c = 0; c < NSCH; ++c) {
      const long idx = ((((long)b * NSCH + c) * NKVH + g) * NREPS + r) * 2;
      const float w = __expf(part_ml[idx] - M);
      L += part_ml[idx + 1] * w;
      o += w * part_out[((((long)b * NSCH + c) * NKVH + g) * NREPS + r) * HDIM + d];
    }
    attn_out[((long)b * NHEADS + g * NREPS + r) * HDIM + d] = o / L;
  }
  grid_barrier(bar);

  // ======== S5: out_part[ks][b][m] = attn_out[b] . oproj[m], K-split 2 ====
  {
    float4* xs = (float4*)shbuf;
    const int t = blockIdx.x;            // exactly 1024 tasks
    const int ks = t / 512, rb = t % 512;
    const int row0 = rb * 8 + wid * 2;
    const int k0 = ks * 512;
    float acc[16][2];
#pragma unroll
    for (int b = 0; b < 16; ++b) { acc[b][0] = 0.f; acc[b][1] = 0.f; }

    const float4* a4 = (const float4*)attn_out;
    for (int c = 0; c < 512; c += KC4) {
      __syncthreads();
#pragma unroll
      for (int i = tid; i < 16 * KC4; i += 256)
        xs[i] = a4[((i >> 6) << 10) + k0 + c + (i & 63)];
      __syncthreads();
      const long wb = (long)row0 * 1024 + k0 + c + lane;
      float4 w0 = oproj4[wb];
      float4 w1 = oproj4[wb + 1024];
#pragma unroll
      for (int b = 0; b < 16; ++b) {
        float4 xv = xs[(b << 6) + lane];
        acc[b][0] = fmaf(w0.x,xv.x,fmaf(w0.y,xv.y,fmaf(w0.z,xv.z,fmaf(w0.w,xv.w,acc[b][0]))));
        acc[b][1] = fmaf(w1.x,xv.x,fmaf(w1.y,xv.y,fmaf(w1.z,xv.z,fmaf(w1.w,xv.w,acc[b][1]))));
      }
    }
#pragma unroll
    for (int b = 0; b < 16; ++b) {
#pragma unroll
      for (int r = 0; r < 2; ++r) {
        float v = acc[b][r];
#pragma unroll
        for (int o = 32; o; o >>= 1) v += __shfl_xor(v, o, 64);
        if (lane == 0)
          out_part[((long)(ks * 16 + b)) * HID + row0 + r] = v;
      }
    }
  }
  grid_barrier(bar);

  // ======== S6: out = out_part[0] + out_part[1] ========
  {
    const int i = blockIdx.x * 256 + tid;
    if (i < BATCH * HID / 4) {
      const float4* p0 = (const float4*)out_part;
      const float4* p1 = (const float4*)(out_part + BATCH * HID);
      float4 a = p0[i], bb = p1[i];
      ((float4*)out)[i] = make_float4(a.x+bb.x, a.y+bb.y, a.z+bb.z, a.w+bb.w);
    }
  }
}

// ---------------------------------------------------------------------------
extern "C" void kernel_launch(void* const* d_in, const int* in_sizes, int n_in,
                              void* d_out, int out_size, void* d_ws, size_t ws_size,
                              hipStream_t stream) {
  const float* x          = (const float*)d_in[0];
  const int*   last_pos   = (const int*)  d_in[1];
  const float* rope_cache = (const float*)d_in[2];
  // d_in[3] = mask: all ones, ignored
  const float* wqkv       = (const float*)d_in[4];
  const float* o_proj_w   = (const float*)d_in[5];
  const float* cache_k    = (const float*)d_in[6];
  const float* cache_v    = (const float*)d_in[7];
  float* out = (float*)d_out;
  float* ws  = (float*)d_ws;

  // zero the grid-barrier state (counter + generation) every launch
  hipMemsetAsync(d_ws, 0, 256, stream);

  fused<<<NBLK, 256, 0, stream>>>(
      (const float4*)x, last_pos, (const float2*)rope_cache,
      (const float4*)wqkv, (const float4*)o_proj_w,
      cache_k, cache_v, out, ws);
}

// Round 5
// 224.823 us; speedup vs baseline: 8.3493x; 8.3493x over previous
//
#include <hip/hip_runtime.h>
#include <hip/hip_bf16.h>

#define BATCH   16
#define SEQ     4096
#define HID     4096
#define NHEADS  32
#define NKVH    8
#define HDIM    128
#define NREPS   4
#define QKV_DIM 6144    // (32 + 2*8) * 128
#define NSCH    16      // S-chunks for flash decode
#define SCH     256     // positions per chunk

// ---------------------------------------------------------------------------
// Kernel 1/5: multi-batch GEMV, no LDS, no barriers, K-split 2.
//   ypart[ks][b][m] = sum_{k in half ks} x[b][k] * w[m][k]
// Block: 256 thr = 4 waves; wave owns 4 rows; lane owns a float4 K-slice.
// x is L2-resident (256 KB) -> read directly; 20 loads in flight per lane.
// ---------------------------------------------------------------------------
__global__ __launch_bounds__(256) void gemv16(
    const float4* __restrict__ x4,   // [16][1024]
    const float4* __restrict__ w4,   // [M][1024]
    float* __restrict__ ypart,       // [2][16][M]
    int M)
{
  const int wid  = threadIdx.x >> 6;
  const int lane = threadIdx.x & 63;
  const int mb   = M / 16;
  const int ks   = blockIdx.x / mb;
  const int rb   = blockIdx.x % mb;
  const int row0 = rb * 16 + wid * 4;
  const int k0   = ks * 512;

  float acc[16][4];
#pragma unroll
  for (int b = 0; b < 16; ++b) { acc[b][0]=0.f; acc[b][1]=0.f; acc[b][2]=0.f; acc[b][3]=0.f; }

  for (int c = 0; c < 512; c += 64) {
    const int kk = k0 + c + lane;
    const long wb = (long)row0 * 1024 + kk;
    float4 w0 = w4[wb];
    float4 w1 = w4[wb + 1024];
    float4 w2 = w4[wb + 2048];
    float4 w3 = w4[wb + 3072];
    float4 xv[16];
#pragma unroll
    for (int b = 0; b < 16; ++b) xv[b] = x4[(b << 10) + kk];
#pragma unroll
    for (int b = 0; b < 16; ++b) {
      acc[b][0] = fmaf(w0.x,xv[b].x,fmaf(w0.y,xv[b].y,fmaf(w0.z,xv[b].z,fmaf(w0.w,xv[b].w,acc[b][0]))));
      acc[b][1] = fmaf(w1.x,xv[b].x,fmaf(w1.y,xv[b].y,fmaf(w1.z,xv[b].z,fmaf(w1.w,xv[b].w,acc[b][1]))));
      acc[b][2] = fmaf(w2.x,xv[b].x,fmaf(w2.y,xv[b].y,fmaf(w2.z,xv[b].z,fmaf(w2.w,xv[b].w,acc[b][2]))));
      acc[b][3] = fmaf(w3.x,xv[b].x,fmaf(w3.y,xv[b].y,fmaf(w3.z,xv[b].z,fmaf(w3.w,xv[b].w,acc[b][3]))));
    }
  }
#pragma unroll
  for (int b = 0; b < 16; ++b) {
#pragma unroll
    for (int r = 0; r < 4; ++r) {
      float v = acc[b][r];
#pragma unroll
      for (int o = 32; o; o >>= 1) v += __shfl_xor(v, o, 64);
      if (lane == 0) ypart[((long)(ks * 16 + b)) * M + row0 + r] = v;
    }
  }
}

// ---------------------------------------------------------------------------
// Kernel 2: reduce qkv K-split halves + RoPE (q,k) + RMSNorm (q,k) + pass (v).
// ---------------------------------------------------------------------------
__global__ __launch_bounds__(64) void rope_rms(
    const float*  __restrict__ qp0,
    const float*  __restrict__ qp1,
    const int*    __restrict__ last_pos,
    const float2* __restrict__ rope2,   // [SEQ][64]
    float* __restrict__ proc)           // [16][6144]
{
  const int b    = blockIdx.x / 48;
  const int hh   = blockIdx.x % 48;     // 0..31 q, 32..39 k, 40..47 v
  const int lane = threadIdx.x;
  const int off  = b * QKV_DIM + hh * HDIM;

  float2 e0 = ((const float2*)(qp0 + off))[lane];
  float2 e1 = ((const float2*)(qp1 + off))[lane];
  float ex = e0.x + e1.x, ey = e0.y + e1.y;
  float r0 = ex, r1 = ey;
  if (hh < 40) {
    const int pos = last_pos[b];
    float2 cs = rope2[pos * 64 + lane];
    r0 = ex * cs.x - ey * cs.y;
    r1 = ey * cs.x + ex * cs.y;
    float ss = r0 * r0 + r1 * r1;
#pragma unroll
    for (int o = 32; o; o >>= 1) ss += __shfl_xor(ss, o, 64);
    float scl = rsqrtf(ss * (1.0f / 128.0f) + 1e-5f);
    r0 *= scl; r1 *= scl;
  }
  ((float2*)(proc + off))[lane] = make_float2(r0, r1);
}

// ---------------------------------------------------------------------------
// Kernel 3: attention partials. Block = (b, g, ch); 256 positions per chunk.
// Phase A: half-wave per position pair (dual unroll, 8 loads in flight).
// ---------------------------------------------------------------------------
__global__ __launch_bounds__(256) void attn_partial(
    const float* __restrict__ proc,
    const float* __restrict__ cache_k,   // [16][SEQ][8][128]
    const float* __restrict__ cache_v,
    const int*   __restrict__ last_pos,
    float* __restrict__ part_out,        // [16][8][NSCH][4][128]
    float* __restrict__ part_ml)         // [16][8][NSCH][4][2]
{
  __shared__ float sc[NREPS][SCH];   // 4 KB
  __shared__ float ps[8][512];       // 16 KB
  __shared__ float red[4][8];

  const int ch  = blockIdx.x & (NSCH - 1);
  const int g   = (blockIdx.x >> 4) & 7;
  const int b   = blockIdx.x >> 7;
  const int tid = threadIdx.x;
  const int pos = last_pos[b];
  const int s0  = ch * SCH;

  const float4* knewg = (const float4*)(proc + b * QKV_DIM + (NHEADS + g) * HDIM);
  const float4* vnewg = (const float4*)(proc + b * QKV_DIM + (NHEADS + NKVH + g) * HDIM);
  const float4* kg = (const float4*)(cache_k + ((long)b * SEQ * NKVH) * HDIM) + g * 32;
  const float4* vg = (const float4*)(cache_v + ((long)b * SEQ * NKVH) * HDIM) + g * 32;

  const int hw  = tid >> 5;        // 0..7 half-wave
  const int sub = tid & 31;
  const int r   = sub >> 3;        // rep 0..3
  const int sl  = sub & 7;         // d-slice 0..7

  const float isq = 0.08838834764831845f;
  float4 ql[4];
#pragma unroll
  for (int t = 0; t < 4; ++t) {
    float4 q = *(const float4*)(proc + b * QKV_DIM + (g * NREPS + r) * HDIM + sl * 16 + t * 4);
    ql[t] = make_float4(q.x * isq, q.y * isq, q.z * isq, q.w * isq);
  }

  // ---- Phase A: scores, two positions per iteration ----
  float m = -3e38f;
  for (int i = hw; i < SCH; i += 16) {
    const int sA = s0 + i, sB = s0 + i + 8;
    const float4* rowA = (sA == pos) ? knewg : (kg + (long)sA * 256);
    const float4* rowB = (sB == pos) ? knewg : (kg + (long)sB * 256);
    float4 kA0 = rowA[sl*4+0], kA1 = rowA[sl*4+1], kA2 = rowA[sl*4+2], kA3 = rowA[sl*4+3];
    float4 kB0 = rowB[sl*4+0], kB1 = rowB[sl*4+1], kB2 = rowB[sl*4+2], kB3 = rowB[sl*4+3];
    float dA = kA0.x*ql[0].x + kA0.y*ql[0].y + kA0.z*ql[0].z + kA0.w*ql[0].w
             + kA1.x*ql[1].x + kA1.y*ql[1].y + kA1.z*ql[1].z + kA1.w*ql[1].w
             + kA2.x*ql[2].x + kA2.y*ql[2].y + kA2.z*ql[2].z + kA2.w*ql[2].w
             + kA3.x*ql[3].x + kA3.y*ql[3].y + kA3.z*ql[3].z + kA3.w*ql[3].w;
    float dB = kB0.x*ql[0].x + kB0.y*ql[0].y + kB0.z*ql[0].z + kB0.w*ql[0].w
             + kB1.x*ql[1].x + kB1.y*ql[1].y + kB1.z*ql[1].z + kB1.w*ql[1].w
             + kB2.x*ql[2].x + kB2.y*ql[2].y + kB2.z*ql[2].z + kB2.w*ql[2].w
             + kB3.x*ql[3].x + kB3.y*ql[3].y + kB3.z*ql[3].z + kB3.w*ql[3].w;
    dA += __shfl_xor(dA, 1); dA += __shfl_xor(dA, 2); dA += __shfl_xor(dA, 4);
    dB += __shfl_xor(dB, 1); dB += __shfl_xor(dB, 2); dB += __shfl_xor(dB, 4);
    if (sl == 0) { sc[r][i] = dA; sc[r][i + 8] = dB; }
    m = fmaxf(m, fmaxf(dA, dB));
  }
  if (sl == 0) red[r][hw] = m;
  __syncthreads();

  float m_r[4];
#pragma unroll
  for (int r2 = 0; r2 < 4; ++r2) {
    float mm = red[r2][0];
#pragma unroll
    for (int h2 = 1; h2 < 8; ++h2) mm = fmaxf(mm, red[r2][h2]);
    m_r[r2] = mm;
  }

  // ---- exp + partial sums ----
  float lsum[4] = {0.f, 0.f, 0.f, 0.f};
  for (int i = tid; i < SCH; i += 256) {
#pragma unroll
    for (int r2 = 0; r2 < 4; ++r2) {
      float e = __expf(sc[r2][i] - m_r[r2]);
      sc[r2][i] = e;
      lsum[r2] += e;
    }
  }
  __syncthreads();
  const int wid  = tid >> 6;
  const int lane = tid & 63;
#pragma unroll
  for (int r2 = 0; r2 < 4; ++r2) {
    float v = lsum[r2];
#pragma unroll
    for (int o = 32; o; o >>= 1) v += __shfl_xor(v, o, 64);
    if (lane == 0) red[r2][wid] = v;
  }
  __syncthreads();
  float l_r[4];
#pragma unroll
  for (int r2 = 0; r2 < 4; ++r2)
    l_r[r2] = (red[r2][0] + red[r2][1]) + (red[r2][2] + red[r2][3]);

  // ---- Phase B: out[r][:] += p[r][s] * v[s][:], dual unroll ----
  const int slp = tid >> 5;
  const int dq  = sub;
  float4 a0 = {0,0,0,0}, a1 = {0,0,0,0}, a2 = {0,0,0,0}, a3 = {0,0,0,0};
  for (int i = slp * 32; i < slp * 32 + 32; i += 2) {
    const int sA = s0 + i, sB = s0 + i + 1;
    const float4* rA = (sA == pos) ? vnewg : (vg + (long)sA * 256);
    const float4* rB = (sB == pos) ? vnewg : (vg + (long)sB * 256);
    float4 vA = rA[dq], vB = rB[dq];
    float p0A = sc[0][i], p1A = sc[1][i], p2A = sc[2][i], p3A = sc[3][i];
    float p0B = sc[0][i+1], p1B = sc[1][i+1], p2B = sc[2][i+1], p3B = sc[3][i+1];
    a0.x += p0A*vA.x; a0.y += p0A*vA.y; a0.z += p0A*vA.z; a0.w += p0A*vA.w;
    a1.x += p1A*vA.x; a1.y += p1A*vA.y; a1.z += p1A*vA.z; a1.w += p1A*vA.w;
    a2.x += p2A*vA.x; a2.y += p2A*vA.y; a2.z += p2A*vA.z; a2.w += p2A*vA.w;
    a3.x += p3A*vA.x; a3.y += p3A*vA.y; a3.z += p3A*vA.z; a3.w += p3A*vA.w;
    a0.x += p0B*vB.x; a0.y += p0B*vB.y; a0.z += p0B*vB.z; a0.w += p0B*vB.w;
    a1.x += p1B*vB.x; a1.y += p1B*vB.y; a1.z += p1B*vB.z; a1.w += p1B*vB.w;
    a2.x += p2B*vB.x; a2.y += p2B*vB.y; a2.z += p2B*vB.z; a2.w += p2B*vB.w;
    a3.x += p3B*vB.x; a3.y += p3B*vB.y; a3.z += p3B*vB.z; a3.w += p3B*vB.w;
  }
  *(float4*)&ps[slp][0 * 128 + dq * 4] = a0;
  *(float4*)&ps[slp][1 * 128 + dq * 4] = a1;
  *(float4*)&ps[slp][2 * 128 + dq * 4] = a2;
  *(float4*)&ps[slp][3 * 128 + dq * 4] = a3;
  __syncthreads();

  const long base = ((((long)b * NKVH + g) * NSCH + ch) * NREPS) * HDIM;
  for (int idx = tid; idx < 512; idx += 256) {
    float v = 0.f;
#pragma unroll
    for (int s2 = 0; s2 < 8; ++s2) v += ps[s2][idx];
    part_out[base + idx] = v;
  }
  if (tid < 4) {
    float mm = tid==0 ? m_r[0] : tid==1 ? m_r[1] : tid==2 ? m_r[2] : m_r[3];
    float ll = tid==0 ? l_r[0] : tid==1 ? l_r[1] : tid==2 ? l_r[2] : l_r[3];
    const long mlb = (((((long)b * NKVH + g) * NSCH + ch) * NREPS) + tid) * 2;
    part_ml[mlb]     = mm;
    part_ml[mlb + 1] = ll;
  }
}

// ---------------------------------------------------------------------------
// Kernel 4: combine chunk partials. Block per (b, g, r); 128 threads over d.
// ---------------------------------------------------------------------------
__global__ __launch_bounds__(128) void attn_combine(
    const float* __restrict__ part_out,  // [16][8][NSCH][4][128]
    const float* __restrict__ part_ml,   // [16][8][NSCH][4][2]
    float* __restrict__ attn_out)        // [16][4096]
{
  const int r = blockIdx.x & 3;
  const int g = (blockIdx.x >> 2) & 7;
  const int b = blockIdx.x >> 5;
  const int d = threadIdx.x;

  float M = -3e38f;
#pragma unroll
  for (int c = 0; c < NSCH; ++c) {
    const long idx = ((((long)b * NKVH + g) * NSCH + c) * NREPS + r) * 2;
    M = fmaxf(M, part_ml[idx]);
  }
  float L = 0.f, o = 0.f;
#pragma unroll
  for (int c = 0; c < NSCH; ++c) {
    const long idx = ((((long)b * NKVH + g) * NSCH + c) * NREPS + r) * 2;
    const float w = __expf(part_ml[idx] - M);
    L += part_ml[idx + 1] * w;
    o += w * part_out[((((long)b * NKVH + g) * NSCH + c) * NREPS + r) * HDIM + d];
  }
  attn_out[((long)b * NHEADS + g * NREPS + r) * HDIM + d] = o / L;
}

// ---------------------------------------------------------------------------
// Kernel 5: add the two o_proj K-split halves -> final output
// ---------------------------------------------------------------------------
__global__ __launch_bounds__(256) void addhalves(
    const float4* __restrict__ p0, const float4* __restrict__ p1,
    float4* __restrict__ o, int n4)
{
  int i = blockIdx.x * 256 + threadIdx.x;
  if (i < n4) {
    float4 a = p0[i], bb = p1[i];
    o[i] = make_float4(a.x+bb.x, a.y+bb.y, a.z+bb.z, a.w+bb.w);
  }
}

// ---------------------------------------------------------------------------
extern "C" void kernel_launch(void* const* d_in, const int* in_sizes, int n_in,
                              void* d_out, int out_size, void* d_ws, size_t ws_size,
                              hipStream_t stream) {
  const float* x          = (const float*)d_in[0];   // [16][1][4096]
  const int*   last_pos   = (const int*)  d_in[1];   // [16]
  const float* rope_cache = (const float*)d_in[2];   // [4096][64][2]
  // d_in[3] = mask: all ones, ignored
  const float* wqkv       = (const float*)d_in[4];   // [6144][4096]
  const float* o_proj_w   = (const float*)d_in[5];   // [4096][4096]
  const float* cache_k    = (const float*)d_in[6];   // [16][4096][8][128]
  const float* cache_v    = (const float*)d_in[7];
  float* out = (float*)d_out;                        // [16][4096]
  float* ws  = (float*)d_ws;

  float* qkv_part = ws;                  // 2*16*6144       = 196608 f
  float* proc     = ws + 196608;         // 16*6144         =  98304 f
  float* part_out = ws + 294912;         // 16*8*16*4*128   = 1048576 f
  float* part_ml  = ws + 1343488;        // 16*8*16*4*2     =  16384 f
  float* attn_out = ws + 1359872;        // 16*4096         =  65536 f
  float* out_part = ws + 1425408;        // 2*16*4096       = 131072 f

  // 1) qkv partials = x @ wqkv^T (K split in 2)
  gemv16<<<(QKV_DIM / 16) * 2, 256, 0, stream>>>(
      (const float4*)x, (const float4*)wqkv, qkv_part, QKV_DIM);
  // 2) reduce halves + rope + rmsnorm
  rope_rms<<<BATCH * 48, 64, 0, stream>>>(
      qkv_part, qkv_part + BATCH * QKV_DIM, last_pos,
      (const float2*)rope_cache, proc);
  // 3) attention partials (split-S flash decode)
  attn_partial<<<BATCH * NKVH * NSCH, 256, 0, stream>>>(
      proc, cache_k, cache_v, last_pos, part_out, part_ml);
  // 4) combine
  attn_combine<<<BATCH * NKVH * NREPS, 128, 0, stream>>>(
      part_out, part_ml, attn_out);
  // 5) o_proj partials (K split in 2)
  gemv16<<<(HID / 16) * 2, 256, 0, stream>>>(
      (const float4*)attn_out, (const float4*)o_proj_w, out_part, HID);
  // 6) add halves -> out
  addhalves<<<(BATCH * HID / 4 + 255) / 256, 256, 0, stream>>>(
      (const float4*)out_part, (const float4*)(out_part + BATCH * HID),
      (float4*)out, BATCH * HID / 4);
}